// Round 3
// baseline (1349.521 us; speedup 1.0000x reference)
//
#include <hip/hip_runtime.h>
#include <cmath>

#define N_NODES   100000
#define N_EDGES   1600000
#define N_FEATS   128
#define HIDDEN    64
#define N_CLASSES 40
#define N_LAYERS  8
#define ALPHA     0.1f
#define LAMDA     0.5f

#define SCAN_ITEMS 8
#define SCAN_BLK   256
#define SCAN_TILE  (SCAN_ITEMS * SCAN_BLK)                  // 2048
#define SCAN_NBLK  ((N_NODES + SCAN_TILE - 1) / SCAN_TILE)  // 49

// ---------------- CSR build ----------------

__global__ __launch_bounds__(256) void k_zero_deg(int* __restrict__ deg) {
    int i = blockIdx.x * 256 + threadIdx.x;
    if (i < N_NODES) deg[i] = 0;
}

__global__ __launch_bounds__(256) void k_count_deg(const int* __restrict__ col,
                                                   int* __restrict__ deg) {
    int e = blockIdx.x * 256 + threadIdx.x;
    if (e < N_EDGES) atomicAdd(&deg[col[e]], 1);
}

// block-level exclusive scan of deg -> rowptr (partial), block totals -> bsum
__global__ __launch_bounds__(SCAN_BLK) void k_scan1(const int* __restrict__ deg,
                                                    int* __restrict__ rowptr,
                                                    int* __restrict__ bsum) {
    __shared__ int sc[SCAN_BLK];
    const int t = threadIdx.x;
    const int base = blockIdx.x * SCAN_TILE + t * SCAN_ITEMS;
    int v[SCAN_ITEMS];
    int tsum = 0;
#pragma unroll
    for (int j = 0; j < SCAN_ITEMS; ++j) {
        v[j] = (base + j < N_NODES) ? deg[base + j] : 0;
        tsum += v[j];
    }
    sc[t] = tsum;
    __syncthreads();
    for (int off = 1; off < SCAN_BLK; off <<= 1) {
        int x = (t >= off) ? sc[t - off] : 0;
        __syncthreads();
        sc[t] += x;
        __syncthreads();
    }
    int run = sc[t] - tsum;
#pragma unroll
    for (int j = 0; j < SCAN_ITEMS; ++j) {
        if (base + j < N_NODES) rowptr[base + j] = run;
        run += v[j];
    }
    if (t == SCAN_BLK - 1) bsum[blockIdx.x] = sc[SCAN_BLK - 1];
}

__global__ __launch_bounds__(SCAN_BLK) void k_scan2(int* __restrict__ bsum) {
    __shared__ int sc[SCAN_BLK];
    const int t = threadIdx.x;
    int v = (t < SCAN_NBLK) ? bsum[t] : 0;
    sc[t] = v;
    __syncthreads();
    for (int off = 1; off < SCAN_BLK; off <<= 1) {
        int x = (t >= off) ? sc[t - off] : 0;
        __syncthreads();
        sc[t] += x;
        __syncthreads();
    }
    if (t < SCAN_NBLK) bsum[t] = sc[t] - v;
}

__global__ __launch_bounds__(256) void k_scan3(int* __restrict__ rowptr,
                                               const int* __restrict__ bsum,
                                               int* __restrict__ cursor) {
    int i = blockIdx.x * 256 + threadIdx.x;
    if (i < N_NODES) {
        int r = rowptr[i] + bsum[i / SCAN_TILE];
        rowptr[i] = r;
        cursor[i] = r;
    }
    if (i == 0) rowptr[N_NODES] = N_EDGES;
}

__global__ __launch_bounds__(256) void k_dinv(const int* __restrict__ deg,
                                              float* __restrict__ dinv) {
    int i = blockIdx.x * 256 + threadIdx.x;
    if (i < N_NODES) dinv[i] = rsqrtf(1.0f + (float)deg[i]);   // +1 self-loop
}

// fill: only the source index (4B per edge); weights recomputed on the fly later
__global__ __launch_bounds__(256) void k_fill(const int* __restrict__ row,
                                              const int* __restrict__ col,
                                              int* __restrict__ cursor,
                                              int* __restrict__ csr_src) {
    int e = blockIdx.x * 256 + threadIdx.x;
    if (e < N_EDGES) {
        int r = row[e], c = col[e];
        int pos = atomicAdd(&cursor[c], 1);
        csr_src[pos] = r;
    }
}

// ---------------- input GEMM: h = relu(x @ W0 + b0), h0 = h ----------------

__global__ __launch_bounds__(256) void k_gemm_in(const float* __restrict__ x,
                                                 const float* __restrict__ W0,
                                                 const float* __restrict__ b0,
                                                 float* __restrict__ h,
                                                 float* __restrict__ h0) {
    __shared__ float sW[N_FEATS * HIDDEN];   // 32 KB
    __shared__ float sX[64 * N_FEATS];       // 32 KB
    const int v0 = blockIdx.x * 64;
    const bool full = (v0 + 64 <= N_NODES);

    const float4* W4 = (const float4*)W0;
    for (int idx = threadIdx.x; idx < (N_FEATS * HIDDEN) / 4; idx += 256)
        ((float4*)sW)[idx] = W4[idx];
    if (full) {
        const float4* X4 = (const float4*)(x + (size_t)v0 * N_FEATS);
        for (int idx = threadIdx.x; idx < (64 * N_FEATS) / 4; idx += 256)
            ((float4*)sX)[idx] = X4[idx];
    } else {
        for (int idx = threadIdx.x; idx < 64 * N_FEATS; idx += 256) {
            int r = idx >> 7, k = idx & 127;
            int v = v0 + r;
            sX[idx] = (v < N_NODES) ? x[(size_t)v * N_FEATS + k] : 0.0f;
        }
    }
    __syncthreads();

    const int c  = threadIdx.x & 63;
    const int r0 = threadIdx.x >> 6;   // 0..3
    float acc[16];
#pragma unroll
    for (int j = 0; j < 16; ++j) acc[j] = 0.0f;

    for (int k = 0; k < N_FEATS; ++k) {
        float w = sW[k * HIDDEN + c];
#pragma unroll
        for (int j = 0; j < 16; ++j)
            acc[j] += sX[(r0 + 4 * j) * N_FEATS + k] * w;
    }

    const float bias = b0[c];
#pragma unroll
    for (int j = 0; j < 16; ++j) {
        int v = v0 + r0 + 4 * j;
        if (v < N_NODES) {
            float val = fmaxf(acc[j] + bias, 0.0f);
            h[(size_t)v * HIDDEN + c]  = val;
            h0[(size_t)v * HIDDEN + c] = val;
        }
    }
}

// ---------------- fused layer: h_out = relu(beta*(S@W) + (1-beta)*S) ----------------
// where S = (1-a)*A_hat*h_in + a*h0, built directly in LDS.
// block = 64 nodes, 4 waves; wave w handles nodes [w*16, w*16+16) in phase 1.

__global__ __launch_bounds__(256) void k_layer(const int* __restrict__ rowptr,
                                               const int* __restrict__ csr_src,
                                               const float* __restrict__ dinv,
                                               const float* __restrict__ h_in,
                                               const float* __restrict__ h0,
                                               const float* __restrict__ W,
                                               float beta,
                                               float* __restrict__ h_out) {
    __shared__ float sW[HIDDEN * HIDDEN];   // 16 KB
    __shared__ float sS[64 * HIDDEN];       // 16 KB
    const int v0   = blockIdx.x * 64;
    const int lane = threadIdx.x & 63;
    const int wv   = threadIdx.x >> 6;      // 0..3

    const float4* W4 = (const float4*)W;
    for (int idx = threadIdx.x; idx < (HIDDEN * HIDDEN) / 4; idx += 256)
        ((float4*)sW)[idx] = W4[idx];

    // ---- phase 1: SpMM into LDS ----
    for (int i = 0; i < 16; ++i) {
        const int nl   = wv * 16 + i;       // local row 0..63
        const int node = v0 + nl;
        float acc = 0.0f;
        if (node < N_NODES) {
            const float  d  = dinv[node];
            const float  wd = (1.0f - ALPHA) * d;
            const size_t ib = (size_t)node * HIDDEN + lane;
            acc = (1.0f - ALPHA) * d * d * h_in[ib] + ALPHA * h0[ib];

            const int e0 = rowptr[node];
            const int e1 = rowptr[node + 1];
            for (int eb = e0; eb < e1; eb += 64) {
                int n = e1 - eb;
                if (n > 64) n = 64;
                int   idx = 0;
                float w   = 0.0f;
                if (lane < n) {
                    idx = csr_src[eb + lane];
                    w   = wd * dinv[idx];
                }
                int j = 0;
                for (; j + 4 <= n; j += 4) {
                    int s0 = __shfl(idx, j),     s1 = __shfl(idx, j + 1);
                    int s2 = __shfl(idx, j + 2), s3 = __shfl(idx, j + 3);
                    float w0 = __shfl(w, j),     w1 = __shfl(w, j + 1);
                    float w2 = __shfl(w, j + 2), w3 = __shfl(w, j + 3);
                    float x0 = h_in[(size_t)s0 * HIDDEN + lane];
                    float x1 = h_in[(size_t)s1 * HIDDEN + lane];
                    float x2 = h_in[(size_t)s2 * HIDDEN + lane];
                    float x3 = h_in[(size_t)s3 * HIDDEN + lane];
                    acc += w0 * x0;
                    acc += w1 * x1;
                    acc += w2 * x2;
                    acc += w3 * x3;
                }
                for (; j < n; ++j) {
                    int   s  = __shfl(idx, j);
                    float ww = __shfl(w, j);
                    acc += ww * h_in[(size_t)s * HIDDEN + lane];
                }
            }
        }
        sS[nl * HIDDEN + lane] = acc;
    }
    __syncthreads();

    // ---- phase 2: GEMM + epilogue (R2-proven access pattern) ----
    float acc[16];
#pragma unroll
    for (int j = 0; j < 16; ++j) acc[j] = 0.0f;

    for (int k = 0; k < HIDDEN; ++k) {
        float w = sW[k * HIDDEN + lane];
#pragma unroll
        for (int j = 0; j < 16; ++j)
            acc[j] += sS[(wv + 4 * j) * HIDDEN + k] * w;
    }

#pragma unroll
    for (int j = 0; j < 16; ++j) {
        int r = wv + 4 * j;
        int v = v0 + r;
        if (v < N_NODES) {
            float s   = sS[r * HIDDEN + lane];
            float val = fmaxf(beta * acc[j] + (1.0f - beta) * s, 0.0f);
            h_out[(size_t)v * HIDDEN + lane] = val;
        }
    }
}

// ---------------- output GEMM: out = h @ W_out + b_out ----------------

__global__ __launch_bounds__(256) void k_gemm_out(const float* __restrict__ h,
                                                  const float* __restrict__ Wout,
                                                  const float* __restrict__ bout,
                                                  float* __restrict__ out) {
    __shared__ float sW[HIDDEN * N_CLASSES];  // 10 KB
    __shared__ float sH[64 * HIDDEN];         // 16 KB
    const int v0 = blockIdx.x * 64;

    for (int idx = threadIdx.x; idx < HIDDEN * N_CLASSES; idx += 256)
        sW[idx] = Wout[idx];
    for (int idx = threadIdx.x; idx < 64 * HIDDEN; idx += 256) {
        int r = idx >> 6, k = idx & 63;
        int v = v0 + r;
        sH[idx] = (v < N_NODES) ? h[(size_t)v * HIDDEN + k] : 0.0f;
    }
    __syncthreads();

    for (int idx = threadIdx.x; idx < 64 * N_CLASSES; idx += 256) {
        int r = idx / N_CLASSES, c = idx % N_CLASSES;
        int v = v0 + r;
        if (v < N_NODES) {
            float acc = bout[c];
#pragma unroll 8
            for (int k = 0; k < HIDDEN; ++k)
                acc += sH[r * HIDDEN + k] * sW[k * N_CLASSES + c];
            out[(size_t)v * N_CLASSES + c] = acc;
        }
    }
}

// ---------------- launch ----------------

extern "C" void kernel_launch(void* const* d_in, const int* in_sizes, int n_in,
                              void* d_out, int out_size, void* d_ws, size_t ws_size,
                              hipStream_t stream) {
    const float* x    = (const float*)d_in[0];
    const int*   ei   = (const int*)d_in[1];
    const float* W0   = (const float*)d_in[2];
    const float* b0   = (const float*)d_in[3];
    const float* Wl   = (const float*)d_in[4];
    const float* Wout = (const float*)d_in[5];
    const float* bout = (const float*)d_in[6];
    float* out = (float*)d_out;

    const int* row = ei;             // edge_index[0] = source
    const int* col = ei + N_EDGES;   // edge_index[1] = target

    char* ws = (char*)d_ws;
    size_t off = 0;
    auto alloc = [&](size_t bytes) -> void* {
        void* p = ws + off;
        off += (bytes + 255) & ~(size_t)255;
        return p;
    };
    int*   deg     = (int*)alloc((size_t)N_NODES * 4);
    int*   rowptr  = (int*)alloc((size_t)(N_NODES + 1) * 4);
    int*   cursor  = (int*)alloc((size_t)N_NODES * 4);
    int*   bsum    = (int*)alloc((size_t)SCAN_NBLK * 4);
    int*   csr_src = (int*)alloc((size_t)N_EDGES * 4);
    float* dinv    = (float*)alloc((size_t)N_NODES * 4);
    float* h0      = (float*)alloc((size_t)N_NODES * HIDDEN * 4);
    float* hA      = (float*)alloc((size_t)N_NODES * HIDDEN * 4);
    float* hB      = (float*)alloc((size_t)N_NODES * HIDDEN * 4);

    const int gN   = (N_NODES + 255) / 256;
    const int gE   = (N_EDGES + 255) / 256;
    const int gRow = (N_NODES + 63) / 64;

    // CSR build (by target node)
    k_zero_deg <<<gN, 256, 0, stream>>>(deg);
    k_count_deg<<<gE, 256, 0, stream>>>(col, deg);
    k_scan1    <<<SCAN_NBLK, SCAN_BLK, 0, stream>>>(deg, rowptr, bsum);
    k_scan2    <<<1, SCAN_BLK, 0, stream>>>(bsum);
    k_scan3    <<<gN, 256, 0, stream>>>(rowptr, bsum, cursor);
    k_dinv     <<<gN, 256, 0, stream>>>(deg, dinv);
    k_fill     <<<gE, 256, 0, stream>>>(row, col, cursor, csr_src);

    // h = relu(x@W0 + b0); h0 = h
    k_gemm_in<<<gRow, 256, 0, stream>>>(x, W0, b0, hA, h0);

    float* h_in  = hA;
    float* h_out = hB;
    for (int i = 0; i < N_LAYERS; ++i) {
        float beta = logf(LAMDA / (float)(i + 1) + 1.0f);
        k_layer<<<gRow, 256, 0, stream>>>(rowptr, csr_src, dinv, h_in, h0,
                                          Wl + (size_t)i * HIDDEN * HIDDEN,
                                          beta, h_out);
        float* t = h_in; h_in = h_out; h_out = t;
    }

    // out = h @ W_out + b_out
    k_gemm_out<<<gRow, 256, 0, stream>>>(h_in, Wout, bout, out);
}

// Round 4
// 1060.676 us; speedup vs baseline: 1.2723x; 1.2723x over previous
//
#include <hip/hip_runtime.h>
#include <cmath>

#define N_NODES   100000
#define N_EDGES   1600000
#define N_FEATS   128
#define HIDDEN    64
#define N_CLASSES 40
#define N_LAYERS  8
#define ALPHA     0.1f
#define LAMDA     0.5f

#define SCAN_ITEMS 8
#define SCAN_BLK   256
#define SCAN_TILE  (SCAN_ITEMS * SCAN_BLK)                  // 2048
#define SCAN_NBLK  ((N_NODES + SCAN_TILE - 1) / SCAN_TILE)  // 49

// ---------------- CSR build ----------------

__global__ __launch_bounds__(256) void k_zero_deg(int* __restrict__ deg) {
    int i = blockIdx.x * 256 + threadIdx.x;
    if (i < N_NODES) deg[i] = 0;
}

// 4 independent atomic chains per thread (latency-bound, not BW-bound)
__global__ __launch_bounds__(256) void k_count_deg(const int* __restrict__ col,
                                                   int* __restrict__ deg) {
    const int G = gridDim.x * 256;
    int e0 = blockIdx.x * 256 + threadIdx.x;
    int e1 = e0 + G, e2 = e1 + G, e3 = e2 + G;
    int c0 = (e0 < N_EDGES) ? col[e0] : -1;
    int c1 = (e1 < N_EDGES) ? col[e1] : -1;
    int c2 = (e2 < N_EDGES) ? col[e2] : -1;
    int c3 = (e3 < N_EDGES) ? col[e3] : -1;
    if (c0 >= 0) atomicAdd(&deg[c0], 1);
    if (c1 >= 0) atomicAdd(&deg[c1], 1);
    if (c2 >= 0) atomicAdd(&deg[c2], 1);
    if (c3 >= 0) atomicAdd(&deg[c3], 1);
}

// block-level exclusive scan of deg -> rowptr (partial), block totals -> bsum
__global__ __launch_bounds__(SCAN_BLK) void k_scan1(const int* __restrict__ deg,
                                                    int* __restrict__ rowptr,
                                                    int* __restrict__ bsum) {
    __shared__ int sc[SCAN_BLK];
    const int t = threadIdx.x;
    const int base = blockIdx.x * SCAN_TILE + t * SCAN_ITEMS;
    int v[SCAN_ITEMS];
    int tsum = 0;
#pragma unroll
    for (int j = 0; j < SCAN_ITEMS; ++j) {
        v[j] = (base + j < N_NODES) ? deg[base + j] : 0;
        tsum += v[j];
    }
    sc[t] = tsum;
    __syncthreads();
    for (int off = 1; off < SCAN_BLK; off <<= 1) {
        int x = (t >= off) ? sc[t - off] : 0;
        __syncthreads();
        sc[t] += x;
        __syncthreads();
    }
    int run = sc[t] - tsum;
#pragma unroll
    for (int j = 0; j < SCAN_ITEMS; ++j) {
        if (base + j < N_NODES) rowptr[base + j] = run;
        run += v[j];
    }
    if (t == SCAN_BLK - 1) bsum[blockIdx.x] = sc[SCAN_BLK - 1];
}

__global__ __launch_bounds__(SCAN_BLK) void k_scan2(int* __restrict__ bsum) {
    __shared__ int sc[SCAN_BLK];
    const int t = threadIdx.x;
    int v = (t < SCAN_NBLK) ? bsum[t] : 0;
    sc[t] = v;
    __syncthreads();
    for (int off = 1; off < SCAN_BLK; off <<= 1) {
        int x = (t >= off) ? sc[t - off] : 0;
        __syncthreads();
        sc[t] += x;
        __syncthreads();
    }
    if (t < SCAN_NBLK) bsum[t] = sc[t] - v;
}

__global__ __launch_bounds__(256) void k_scan3(int* __restrict__ rowptr,
                                               const int* __restrict__ bsum,
                                               int* __restrict__ cursor) {
    int i = blockIdx.x * 256 + threadIdx.x;
    if (i < N_NODES) {
        int r = rowptr[i] + bsum[i / SCAN_TILE];
        rowptr[i] = r;
        cursor[i] = r;
    }
    if (i == 0) rowptr[N_NODES] = N_EDGES;
}

__global__ __launch_bounds__(256) void k_dinv(const int* __restrict__ deg,
                                              float* __restrict__ dinv) {
    int i = blockIdx.x * 256 + threadIdx.x;
    if (i < N_NODES) dinv[i] = rsqrtf(1.0f + (float)deg[i]);   // +1 self-loop
}

// fill with 4 independent chains per thread; stores src + precomputed weight
__global__ __launch_bounds__(256) void k_fill(const int* __restrict__ row,
                                              const int* __restrict__ col,
                                              const float* __restrict__ dinv,
                                              int* __restrict__ cursor,
                                              int* __restrict__ csr_src,
                                              float* __restrict__ csr_w) {
    const int G = gridDim.x * 256;
    int e0 = blockIdx.x * 256 + threadIdx.x;
    int e1 = e0 + G, e2 = e1 + G, e3 = e2 + G;

    int r0 = 0, r1 = 0, r2 = 0, r3 = 0, c0 = -1, c1 = -1, c2 = -1, c3 = -1;
    if (e0 < N_EDGES) { r0 = row[e0]; c0 = col[e0]; }
    if (e1 < N_EDGES) { r1 = row[e1]; c1 = col[e1]; }
    if (e2 < N_EDGES) { r2 = row[e2]; c2 = col[e2]; }
    if (e3 < N_EDGES) { r3 = row[e3]; c3 = col[e3]; }

    int p0 = 0, p1 = 0, p2 = 0, p3 = 0;
    if (c0 >= 0) p0 = atomicAdd(&cursor[c0], 1);
    if (c1 >= 0) p1 = atomicAdd(&cursor[c1], 1);
    if (c2 >= 0) p2 = atomicAdd(&cursor[c2], 1);
    if (c3 >= 0) p3 = atomicAdd(&cursor[c3], 1);

    if (c0 >= 0) { csr_src[p0] = r0; csr_w[p0] = (1.0f - ALPHA) * dinv[r0] * dinv[c0]; }
    if (c1 >= 0) { csr_src[p1] = r1; csr_w[p1] = (1.0f - ALPHA) * dinv[r1] * dinv[c1]; }
    if (c2 >= 0) { csr_src[p2] = r2; csr_w[p2] = (1.0f - ALPHA) * dinv[r2] * dinv[c2]; }
    if (c3 >= 0) { csr_src[p3] = r3; csr_w[p3] = (1.0f - ALPHA) * dinv[r3] * dinv[c3]; }
}

// ---------------- input GEMM: h = relu(x @ W0 + b0), h0 = h ----------------

__global__ __launch_bounds__(256) void k_gemm_in(const float* __restrict__ x,
                                                 const float* __restrict__ W0,
                                                 const float* __restrict__ b0,
                                                 float* __restrict__ h,
                                                 float* __restrict__ h0) {
    __shared__ float sW[N_FEATS * HIDDEN];   // 32 KB
    __shared__ float sX[64 * N_FEATS];       // 32 KB
    const int v0 = blockIdx.x * 64;
    const bool full = (v0 + 64 <= N_NODES);

    const float4* W4 = (const float4*)W0;
    for (int idx = threadIdx.x; idx < (N_FEATS * HIDDEN) / 4; idx += 256)
        ((float4*)sW)[idx] = W4[idx];
    if (full) {
        const float4* X4 = (const float4*)(x + (size_t)v0 * N_FEATS);
        for (int idx = threadIdx.x; idx < (64 * N_FEATS) / 4; idx += 256)
            ((float4*)sX)[idx] = X4[idx];
    } else {
        for (int idx = threadIdx.x; idx < 64 * N_FEATS; idx += 256) {
            int r = idx >> 7, k = idx & 127;
            int v = v0 + r;
            sX[idx] = (v < N_NODES) ? x[(size_t)v * N_FEATS + k] : 0.0f;
        }
    }
    __syncthreads();

    const int c  = threadIdx.x & 63;
    const int r0 = threadIdx.x >> 6;   // 0..3
    float acc[16];
#pragma unroll
    for (int j = 0; j < 16; ++j) acc[j] = 0.0f;

    for (int k = 0; k < N_FEATS; ++k) {
        float w = sW[k * HIDDEN + c];
#pragma unroll
        for (int j = 0; j < 16; ++j)
            acc[j] += sX[(r0 + 4 * j) * N_FEATS + k] * w;
    }

    const float bias = b0[c];
#pragma unroll
    for (int j = 0; j < 16; ++j) {
        int v = v0 + r0 + 4 * j;
        if (v < N_NODES) {
            float val = fmaxf(acc[j] + bias, 0.0f);
            h[(size_t)v * HIDDEN + c]  = val;
            h0[(size_t)v * HIDDEN + c] = val;
        }
    }
}

// ---------------- fused SpMM: buf = (1-a)*A_hat*h + a*h0 ----------------
// one wave per node; lane l owns feature l; 8 gathers in flight per lane.

__global__ __launch_bounds__(256) void k_spmm(const int* __restrict__ rowptr,
                                              const int* __restrict__ csr_src,
                                              const float* __restrict__ csr_w,
                                              const float* __restrict__ dinv,
                                              const float* __restrict__ h,
                                              const float* __restrict__ h0,
                                              float* __restrict__ buf) {
    const int lane = threadIdx.x & 63;
    const int node = (blockIdx.x * 256 + threadIdx.x) >> 6;
    if (node >= N_NODES) return;

    const int e0 = rowptr[node];
    const int e1 = rowptr[node + 1];
    const float d = dinv[node];
    const size_t ib = (size_t)node * HIDDEN + lane;

    // self-loop + residual
    float acc = (1.0f - ALPHA) * d * d * h[ib] + ALPHA * h0[ib];

    for (int eb = e0; eb < e1; eb += 64) {
        int n = e1 - eb;
        if (n > 64) n = 64;
        int   idx = 0;
        float w   = 0.0f;
        if (lane < n) {
            idx = csr_src[eb + lane];
            w   = csr_w[eb + lane];
        }
        int j = 0;
        for (; j + 8 <= n; j += 8) {
            int   s[8];
            float ww[8];
            float xx[8];
#pragma unroll
            for (int u = 0; u < 8; ++u) {
                s[u]  = __shfl(idx, j + u);
                ww[u] = __shfl(w, j + u);
            }
#pragma unroll
            for (int u = 0; u < 8; ++u)
                xx[u] = h[(size_t)s[u] * HIDDEN + lane];
#pragma unroll
            for (int u = 0; u < 8; ++u)
                acc += ww[u] * xx[u];
        }
        for (; j < n; ++j) {
            int   s  = __shfl(idx, j);
            float ww = __shfl(w, j);
            acc += ww * h[(size_t)s * HIDDEN + lane];
        }
    }
    buf[ib] = acc;
}

// ---------------- layer GEMM: hout = relu(beta*(S@W) + (1-beta)*S) ----------------

__global__ __launch_bounds__(256) void k_gemm_layer(const float* __restrict__ S,
                                                    const float* __restrict__ W,
                                                    float beta,
                                                    float* __restrict__ hout) {
    __shared__ float sW[HIDDEN * HIDDEN];   // 16 KB
    __shared__ float sS[64 * HIDDEN];       // 16 KB
    const int v0 = blockIdx.x * 64;
    const bool full = (v0 + 64 <= N_NODES);

    const float4* W4 = (const float4*)W;
    for (int idx = threadIdx.x; idx < (HIDDEN * HIDDEN) / 4; idx += 256)
        ((float4*)sW)[idx] = W4[idx];
    if (full) {
        const float4* S4 = (const float4*)(S + (size_t)v0 * HIDDEN);
        for (int idx = threadIdx.x; idx < (64 * HIDDEN) / 4; idx += 256)
            ((float4*)sS)[idx] = S4[idx];
    } else {
        for (int idx = threadIdx.x; idx < 64 * HIDDEN; idx += 256) {
            int r = idx >> 6, k = idx & 63;
            int v = v0 + r;
            sS[idx] = (v < N_NODES) ? S[(size_t)v * HIDDEN + k] : 0.0f;
        }
    }
    __syncthreads();

    const int c  = threadIdx.x & 63;
    const int r0 = threadIdx.x >> 6;
    float acc[16];
#pragma unroll
    for (int j = 0; j < 16; ++j) acc[j] = 0.0f;

    for (int k = 0; k < HIDDEN; ++k) {
        float w = sW[k * HIDDEN + c];
#pragma unroll
        for (int j = 0; j < 16; ++j)
            acc[j] += sS[(r0 + 4 * j) * HIDDEN + k] * w;
    }

#pragma unroll
    for (int j = 0; j < 16; ++j) {
        int r = r0 + 4 * j;
        int v = v0 + r;
        if (v < N_NODES) {
            float s   = sS[r * HIDDEN + c];
            float val = fmaxf(beta * acc[j] + (1.0f - beta) * s, 0.0f);
            hout[(size_t)v * HIDDEN + c] = val;
        }
    }
}

// ---------------- output GEMM: out = h @ W_out + b_out ----------------

__global__ __launch_bounds__(256) void k_gemm_out(const float* __restrict__ h,
                                                  const float* __restrict__ Wout,
                                                  const float* __restrict__ bout,
                                                  float* __restrict__ out) {
    __shared__ float sW[HIDDEN * N_CLASSES];  // 10 KB
    __shared__ float sH[64 * HIDDEN];         // 16 KB
    const int v0 = blockIdx.x * 64;

    for (int idx = threadIdx.x; idx < HIDDEN * N_CLASSES; idx += 256)
        sW[idx] = Wout[idx];
    for (int idx = threadIdx.x; idx < 64 * HIDDEN; idx += 256) {
        int r = idx >> 6, k = idx & 63;
        int v = v0 + r;
        sH[idx] = (v < N_NODES) ? h[(size_t)v * HIDDEN + k] : 0.0f;
    }
    __syncthreads();

    for (int idx = threadIdx.x; idx < 64 * N_CLASSES; idx += 256) {
        int r = idx / N_CLASSES, c = idx % N_CLASSES;
        int v = v0 + r;
        if (v < N_NODES) {
            float acc = bout[c];
#pragma unroll 8
            for (int k = 0; k < HIDDEN; ++k)
                acc += sH[r * HIDDEN + k] * sW[k * N_CLASSES + c];
            out[(size_t)v * N_CLASSES + c] = acc;
        }
    }
}

// ---------------- launch ----------------

extern "C" void kernel_launch(void* const* d_in, const int* in_sizes, int n_in,
                              void* d_out, int out_size, void* d_ws, size_t ws_size,
                              hipStream_t stream) {
    const float* x    = (const float*)d_in[0];
    const int*   ei   = (const int*)d_in[1];
    const float* W0   = (const float*)d_in[2];
    const float* b0   = (const float*)d_in[3];
    const float* Wl   = (const float*)d_in[4];
    const float* Wout = (const float*)d_in[5];
    const float* bout = (const float*)d_in[6];
    float* out = (float*)d_out;

    const int* row = ei;             // edge_index[0] = source
    const int* col = ei + N_EDGES;   // edge_index[1] = target

    char* ws = (char*)d_ws;
    size_t off = 0;
    auto alloc = [&](size_t bytes) -> void* {
        void* p = ws + off;
        off += (bytes + 255) & ~(size_t)255;
        return p;
    };
    int*   deg     = (int*)alloc((size_t)N_NODES * 4);
    int*   rowptr  = (int*)alloc((size_t)(N_NODES + 1) * 4);
    int*   cursor  = (int*)alloc((size_t)N_NODES * 4);
    int*   bsum    = (int*)alloc((size_t)SCAN_NBLK * 4);
    int*   csr_src = (int*)alloc((size_t)N_EDGES * 4);
    float* csr_w   = (float*)alloc((size_t)N_EDGES * 4);
    float* dinv    = (float*)alloc((size_t)N_NODES * 4);
    float* h0      = (float*)alloc((size_t)N_NODES * HIDDEN * 4);
    float* hA      = (float*)alloc((size_t)N_NODES * HIDDEN * 4);
    float* hB      = (float*)alloc((size_t)N_NODES * HIDDEN * 4);

    const int gN   = (N_NODES + 255) / 256;
    const int gRow = (N_NODES + 63) / 64;
    const int gSpm = (N_NODES * 64 + 255) / 256;       // wave per node
    const int gE4  = (N_EDGES + 4 * 256 - 1) / (4 * 256);  // 4 edges per thread

    // CSR build (by target node)
    k_zero_deg <<<gN, 256, 0, stream>>>(deg);
    k_count_deg<<<gE4, 256, 0, stream>>>(col, deg);
    k_scan1    <<<SCAN_NBLK, SCAN_BLK, 0, stream>>>(deg, rowptr, bsum);
    k_scan2    <<<1, SCAN_BLK, 0, stream>>>(bsum);
    k_scan3    <<<gN, 256, 0, stream>>>(rowptr, bsum, cursor);
    k_dinv     <<<gN, 256, 0, stream>>>(deg, dinv);
    k_fill     <<<gE4, 256, 0, stream>>>(row, col, dinv, cursor, csr_src, csr_w);

    // h = relu(x@W0 + b0); h0 = h
    k_gemm_in<<<gRow, 256, 0, stream>>>(x, W0, b0, hA, h0);

    float* h   = hA;
    float* buf = hB;
    for (int i = 0; i < N_LAYERS; ++i) {
        float beta = logf(LAMDA / (float)(i + 1) + 1.0f);
        // buf = (1-a)*A_hat*h + a*h0   (self-loop + residual fused)
        k_spmm<<<gSpm, 256, 0, stream>>>(rowptr, csr_src, csr_w, dinv, h, h0, buf);
        // h = relu(beta*(buf@Wl[i]) + (1-beta)*buf)
        k_gemm_layer<<<gRow, 256, 0, stream>>>(buf, Wl + (size_t)i * HIDDEN * HIDDEN,
                                               beta, h);
    }

    // out = h @ W_out + b_out
    k_gemm_out<<<gRow, 256, 0, stream>>>(h, Wout, bout, out);
}

// Round 5
// 1023.733 us; speedup vs baseline: 1.3182x; 1.0361x over previous
//
#include <hip/hip_runtime.h>
#include <cmath>

#define N_NODES   100000
#define N_EDGES   1600000
#define N_FEATS   128
#define HIDDEN    64
#define N_CLASSES 40
#define N_LAYERS  8
#define ALPHA     0.1f
#define LAMDA     0.5f

#define SCAN_ITEMS 8
#define SCAN_BLK   256
#define SCAN_TILE  (SCAN_ITEMS * SCAN_BLK)                  // 2048
#define SCAN_NBLK  ((N_NODES + SCAN_TILE - 1) / SCAN_TILE)  // 49

// ---------------- CSR build ----------------

__global__ __launch_bounds__(256) void k_zero_deg(int* __restrict__ deg) {
    int i = blockIdx.x * 256 + threadIdx.x;
    if (i < N_NODES) deg[i] = 0;
}

// 4 independent atomic chains per thread (latency-bound, not BW-bound)
__global__ __launch_bounds__(256) void k_count_deg(const int* __restrict__ col,
                                                   int* __restrict__ deg) {
    const int G = gridDim.x * 256;
    int e0 = blockIdx.x * 256 + threadIdx.x;
    int e1 = e0 + G, e2 = e1 + G, e3 = e2 + G;
    int c0 = (e0 < N_EDGES) ? col[e0] : -1;
    int c1 = (e1 < N_EDGES) ? col[e1] : -1;
    int c2 = (e2 < N_EDGES) ? col[e2] : -1;
    int c3 = (e3 < N_EDGES) ? col[e3] : -1;
    if (c0 >= 0) atomicAdd(&deg[c0], 1);
    if (c1 >= 0) atomicAdd(&deg[c1], 1);
    if (c2 >= 0) atomicAdd(&deg[c2], 1);
    if (c3 >= 0) atomicAdd(&deg[c3], 1);
}

// block-level exclusive scan of deg -> rowptr (partial), block totals -> bsum
__global__ __launch_bounds__(SCAN_BLK) void k_scan1(const int* __restrict__ deg,
                                                    int* __restrict__ rowptr,
                                                    int* __restrict__ bsum) {
    __shared__ int sc[SCAN_BLK];
    const int t = threadIdx.x;
    const int base = blockIdx.x * SCAN_TILE + t * SCAN_ITEMS;
    int v[SCAN_ITEMS];
    int tsum = 0;
#pragma unroll
    for (int j = 0; j < SCAN_ITEMS; ++j) {
        v[j] = (base + j < N_NODES) ? deg[base + j] : 0;
        tsum += v[j];
    }
    sc[t] = tsum;
    __syncthreads();
    for (int off = 1; off < SCAN_BLK; off <<= 1) {
        int x = (t >= off) ? sc[t - off] : 0;
        __syncthreads();
        sc[t] += x;
        __syncthreads();
    }
    int run = sc[t] - tsum;
#pragma unroll
    for (int j = 0; j < SCAN_ITEMS; ++j) {
        if (base + j < N_NODES) rowptr[base + j] = run;
        run += v[j];
    }
    if (t == SCAN_BLK - 1) bsum[blockIdx.x] = sc[SCAN_BLK - 1];
}

__global__ __launch_bounds__(SCAN_BLK) void k_scan2(int* __restrict__ bsum) {
    __shared__ int sc[SCAN_BLK];
    const int t = threadIdx.x;
    int v = (t < SCAN_NBLK) ? bsum[t] : 0;
    sc[t] = v;
    __syncthreads();
    for (int off = 1; off < SCAN_BLK; off <<= 1) {
        int x = (t >= off) ? sc[t - off] : 0;
        __syncthreads();
        sc[t] += x;
        __syncthreads();
    }
    if (t < SCAN_NBLK) bsum[t] = sc[t] - v;
}

__global__ __launch_bounds__(256) void k_scan3(int* __restrict__ rowptr,
                                               const int* __restrict__ bsum,
                                               int* __restrict__ cursor) {
    int i = blockIdx.x * 256 + threadIdx.x;
    if (i < N_NODES) {
        int r = rowptr[i] + bsum[i / SCAN_TILE];
        rowptr[i] = r;
        cursor[i] = r;
    }
    if (i == 0) rowptr[N_NODES] = N_EDGES;
}

__global__ __launch_bounds__(256) void k_dinv(const int* __restrict__ deg,
                                              float* __restrict__ dinv) {
    int i = blockIdx.x * 256 + threadIdx.x;
    if (i < N_NODES) dinv[i] = rsqrtf(1.0f + (float)deg[i]);   // +1 self-loop
}

// fill: interleaved (src, weight) int2 -> one 8B store per edge (half the dirty lines)
__global__ __launch_bounds__(256) void k_fill(const int* __restrict__ row,
                                              const int* __restrict__ col,
                                              const float* __restrict__ dinv,
                                              int* __restrict__ cursor,
                                              int2* __restrict__ csr) {
    const int G = gridDim.x * 256;
    int e0 = blockIdx.x * 256 + threadIdx.x;
    int e1 = e0 + G, e2 = e1 + G, e3 = e2 + G;

    int r0 = 0, r1 = 0, r2 = 0, r3 = 0, c0 = -1, c1 = -1, c2 = -1, c3 = -1;
    if (e0 < N_EDGES) { r0 = row[e0]; c0 = col[e0]; }
    if (e1 < N_EDGES) { r1 = row[e1]; c1 = col[e1]; }
    if (e2 < N_EDGES) { r2 = row[e2]; c2 = col[e2]; }
    if (e3 < N_EDGES) { r3 = row[e3]; c3 = col[e3]; }

    int p0 = 0, p1 = 0, p2 = 0, p3 = 0;
    if (c0 >= 0) p0 = atomicAdd(&cursor[c0], 1);
    if (c1 >= 0) p1 = atomicAdd(&cursor[c1], 1);
    if (c2 >= 0) p2 = atomicAdd(&cursor[c2], 1);
    if (c3 >= 0) p3 = atomicAdd(&cursor[c3], 1);

    if (c0 >= 0) csr[p0] = make_int2(r0, __float_as_int((1.0f - ALPHA) * dinv[r0] * dinv[c0]));
    if (c1 >= 0) csr[p1] = make_int2(r1, __float_as_int((1.0f - ALPHA) * dinv[r1] * dinv[c1]));
    if (c2 >= 0) csr[p2] = make_int2(r2, __float_as_int((1.0f - ALPHA) * dinv[r2] * dinv[c2]));
    if (c3 >= 0) csr[p3] = make_int2(r3, __float_as_int((1.0f - ALPHA) * dinv[r3] * dinv[c3]));
}

// ---------------- input GEMM: h = relu(x @ W0 + b0), h0 = h ----------------

__global__ __launch_bounds__(256) void k_gemm_in(const float* __restrict__ x,
                                                 const float* __restrict__ W0,
                                                 const float* __restrict__ b0,
                                                 float* __restrict__ h,
                                                 float* __restrict__ h0) {
    __shared__ float sW[N_FEATS * HIDDEN];   // 32 KB
    __shared__ float sX[64 * N_FEATS];       // 32 KB
    const int v0 = blockIdx.x * 64;
    const bool full = (v0 + 64 <= N_NODES);

    const float4* W4 = (const float4*)W0;
    for (int idx = threadIdx.x; idx < (N_FEATS * HIDDEN) / 4; idx += 256)
        ((float4*)sW)[idx] = W4[idx];
    if (full) {
        const float4* X4 = (const float4*)(x + (size_t)v0 * N_FEATS);
        for (int idx = threadIdx.x; idx < (64 * N_FEATS) / 4; idx += 256)
            ((float4*)sX)[idx] = X4[idx];
    } else {
        for (int idx = threadIdx.x; idx < 64 * N_FEATS; idx += 256) {
            int r = idx >> 7, k = idx & 127;
            int v = v0 + r;
            sX[idx] = (v < N_NODES) ? x[(size_t)v * N_FEATS + k] : 0.0f;
        }
    }
    __syncthreads();

    const int c  = threadIdx.x & 63;
    const int r0 = threadIdx.x >> 6;   // 0..3
    float acc[16];
#pragma unroll
    for (int j = 0; j < 16; ++j) acc[j] = 0.0f;

    for (int k = 0; k < N_FEATS; ++k) {
        float w = sW[k * HIDDEN + c];
#pragma unroll
        for (int j = 0; j < 16; ++j)
            acc[j] += sX[(r0 + 4 * j) * N_FEATS + k] * w;
    }

    const float bias = b0[c];
#pragma unroll
    for (int j = 0; j < 16; ++j) {
        int v = v0 + r0 + 4 * j;
        if (v < N_NODES) {
            float val = fmaxf(acc[j] + bias, 0.0f);
            h[(size_t)v * HIDDEN + c]  = val;
            h0[(size_t)v * HIDDEN + c] = val;
        }
    }
}

// ---------------- fused SpMM: buf = (1-a)*A_hat*h + a*h0 ----------------
// one wave per node; lanes 0-31 process even edges, 32-63 odd edges;
// each lane holds a float2 feature pair. 8 dwordx2 gathers (16 edges) in flight.

__global__ __launch_bounds__(256) void k_spmm(const int* __restrict__ rowptr,
                                              const int2* __restrict__ csr,
                                              const float* __restrict__ dinv,
                                              const float* __restrict__ h,
                                              const float* __restrict__ h0,
                                              float* __restrict__ buf) {
    const int lane = threadIdx.x & 63;
    const int l32  = lane & 31;
    const int half = lane >> 5;
    const int node = (blockIdx.x * 256 + threadIdx.x) >> 6;
    if (node >= N_NODES) return;

    const int e0 = rowptr[node];
    const int e1 = rowptr[node + 1];
    const float d = dinv[node];

    float ax, ay;
    if (half == 0) {
        const float2 hv  = *(const float2*)(h  + (size_t)node * HIDDEN + 2 * l32);
        const float2 h0v = *(const float2*)(h0 + (size_t)node * HIDDEN + 2 * l32);
        const float cs = (1.0f - ALPHA) * d * d;
        ax = cs * hv.x + ALPHA * h0v.x;
        ay = cs * hv.y + ALPHA * h0v.y;
    } else {
        ax = 0.0f; ay = 0.0f;
    }

    for (int eb = e0; eb < e1; eb += 64) {
        int n = e1 - eb;
        if (n > 64) n = 64;
        int   idx = 0;
        float w   = 0.0f;
        if (lane < n) {
            int2 e = csr[eb + lane];
            idx = e.x;
            w   = __int_as_float(e.y);
        }
        // lanes beyond n hold (0, 0.0f): shfl from them contributes 0 safely.
        for (int j = 0; j < n; j += 16) {
            int   s[8];
            float ww[8];
            float2 xv[8];
#pragma unroll
            for (int u = 0; u < 8; ++u) {
                int src = j + 2 * u + half;     // < 64 always
                s[u]  = __shfl(idx, src);
                ww[u] = __shfl(w, src);
            }
#pragma unroll
            for (int u = 0; u < 8; ++u)
                xv[u] = *(const float2*)(h + (size_t)s[u] * HIDDEN + 2 * l32);
#pragma unroll
            for (int u = 0; u < 8; ++u) {
                ax += ww[u] * xv[u].x;
                ay += ww[u] * xv[u].y;
            }
        }
    }

    // combine even/odd-edge halves
    ax += __shfl_xor(ax, 32);
    ay += __shfl_xor(ay, 32);
    if (half == 0) {
        float2 o; o.x = ax; o.y = ay;
        *(float2*)(buf + (size_t)node * HIDDEN + 2 * l32) = o;
    }
}

// ---------------- layer GEMM: hout = relu(beta*(S@W) + (1-beta)*S) ----------------

__global__ __launch_bounds__(256) void k_gemm_layer(const float* __restrict__ S,
                                                    const float* __restrict__ W,
                                                    float beta,
                                                    float* __restrict__ hout) {
    __shared__ float sW[HIDDEN * HIDDEN];   // 16 KB
    __shared__ float sS[64 * HIDDEN];       // 16 KB
    const int v0 = blockIdx.x * 64;
    const bool full = (v0 + 64 <= N_NODES);

    const float4* W4 = (const float4*)W;
    for (int idx = threadIdx.x; idx < (HIDDEN * HIDDEN) / 4; idx += 256)
        ((float4*)sW)[idx] = W4[idx];
    if (full) {
        const float4* S4 = (const float4*)(S + (size_t)v0 * HIDDEN);
        for (int idx = threadIdx.x; idx < (64 * HIDDEN) / 4; idx += 256)
            ((float4*)sS)[idx] = S4[idx];
    } else {
        for (int idx = threadIdx.x; idx < 64 * HIDDEN; idx += 256) {
            int r = idx >> 6, k = idx & 63;
            int v = v0 + r;
            sS[idx] = (v < N_NODES) ? S[(size_t)v * HIDDEN + k] : 0.0f;
        }
    }
    __syncthreads();

    const int c  = threadIdx.x & 63;
    const int r0 = threadIdx.x >> 6;
    float acc[16];
#pragma unroll
    for (int j = 0; j < 16; ++j) acc[j] = 0.0f;

    for (int k = 0; k < HIDDEN; ++k) {
        float w = sW[k * HIDDEN + c];
#pragma unroll
        for (int j = 0; j < 16; ++j)
            acc[j] += sS[(r0 + 4 * j) * HIDDEN + k] * w;
    }

#pragma unroll
    for (int j = 0; j < 16; ++j) {
        int r = r0 + 4 * j;
        int v = v0 + r;
        if (v < N_NODES) {
            float s   = sS[r * HIDDEN + c];
            float val = fmaxf(beta * acc[j] + (1.0f - beta) * s, 0.0f);
            hout[(size_t)v * HIDDEN + c] = val;
        }
    }
}

// ---------------- output GEMM: out = h @ W_out + b_out ----------------

__global__ __launch_bounds__(256) void k_gemm_out(const float* __restrict__ h,
                                                  const float* __restrict__ Wout,
                                                  const float* __restrict__ bout,
                                                  float* __restrict__ out) {
    __shared__ float sW[HIDDEN * N_CLASSES];  // 10 KB
    __shared__ float sH[64 * HIDDEN];         // 16 KB
    const int v0 = blockIdx.x * 64;

    for (int idx = threadIdx.x; idx < HIDDEN * N_CLASSES; idx += 256)
        sW[idx] = Wout[idx];
    for (int idx = threadIdx.x; idx < 64 * HIDDEN; idx += 256) {
        int r = idx >> 6, k = idx & 63;
        int v = v0 + r;
        sH[idx] = (v < N_NODES) ? h[(size_t)v * HIDDEN + k] : 0.0f;
    }
    __syncthreads();

    for (int idx = threadIdx.x; idx < 64 * N_CLASSES; idx += 256) {
        int r = idx / N_CLASSES, c = idx % N_CLASSES;
        int v = v0 + r;
        if (v < N_NODES) {
            float acc = bout[c];
#pragma unroll 8
            for (int k = 0; k < HIDDEN; ++k)
                acc += sH[r * HIDDEN + k] * sW[k * N_CLASSES + c];
            out[(size_t)v * N_CLASSES + c] = acc;
        }
    }
}

// ---------------- launch ----------------

extern "C" void kernel_launch(void* const* d_in, const int* in_sizes, int n_in,
                              void* d_out, int out_size, void* d_ws, size_t ws_size,
                              hipStream_t stream) {
    const float* x    = (const float*)d_in[0];
    const int*   ei   = (const int*)d_in[1];
    const float* W0   = (const float*)d_in[2];
    const float* b0   = (const float*)d_in[3];
    const float* Wl   = (const float*)d_in[4];
    const float* Wout = (const float*)d_in[5];
    const float* bout = (const float*)d_in[6];
    float* out = (float*)d_out;

    const int* row = ei;             // edge_index[0] = source
    const int* col = ei + N_EDGES;   // edge_index[1] = target

    char* ws = (char*)d_ws;
    size_t off = 0;
    auto alloc = [&](size_t bytes) -> void* {
        void* p = ws + off;
        off += (bytes + 255) & ~(size_t)255;
        return p;
    };
    int*   deg    = (int*)alloc((size_t)N_NODES * 4);
    int*   rowptr = (int*)alloc((size_t)(N_NODES + 1) * 4);
    int*   cursor = (int*)alloc((size_t)N_NODES * 4);
    int*   bsum   = (int*)alloc((size_t)SCAN_NBLK * 4);
    int2*  csr    = (int2*)alloc((size_t)N_EDGES * 8);
    float* dinv   = (float*)alloc((size_t)N_NODES * 4);
    float* h0     = (float*)alloc((size_t)N_NODES * HIDDEN * 4);
    float* hA     = (float*)alloc((size_t)N_NODES * HIDDEN * 4);
    float* hB     = (float*)alloc((size_t)N_NODES * HIDDEN * 4);

    const int gN   = (N_NODES + 255) / 256;
    const int gRow = (N_NODES + 63) / 64;
    const int gSpm = (N_NODES * 64 + 255) / 256;           // wave per node
    const int gE4  = (N_EDGES + 4 * 256 - 1) / (4 * 256);  // 4 edges per thread

    // CSR build (by target node)
    k_zero_deg <<<gN, 256, 0, stream>>>(deg);
    k_count_deg<<<gE4, 256, 0, stream>>>(col, deg);
    k_scan1    <<<SCAN_NBLK, SCAN_BLK, 0, stream>>>(deg, rowptr, bsum);
    k_scan2    <<<1, SCAN_BLK, 0, stream>>>(bsum);
    k_scan3    <<<gN, 256, 0, stream>>>(rowptr, bsum, cursor);
    k_dinv     <<<gN, 256, 0, stream>>>(deg, dinv);
    k_fill     <<<gE4, 256, 0, stream>>>(row, col, dinv, cursor, csr);

    // h = relu(x@W0 + b0); h0 = h
    k_gemm_in<<<gRow, 256, 0, stream>>>(x, W0, b0, hA, h0);

    float* h   = hA;
    float* buf = hB;
    for (int i = 0; i < N_LAYERS; ++i) {
        float beta = logf(LAMDA / (float)(i + 1) + 1.0f);
        // buf = (1-a)*A_hat*h + a*h0   (self-loop + residual fused)
        k_spmm<<<gSpm, 256, 0, stream>>>(rowptr, csr, dinv, h, h0, buf);
        // h = relu(beta*(buf@Wl[i]) + (1-beta)*buf)
        k_gemm_layer<<<gRow, 256, 0, stream>>>(buf, Wl + (size_t)i * HIDDEN * HIDDEN,
                                               beta, h);
    }

    // out = h @ W_out + b_out
    k_gemm_out<<<gRow, 256, 0, stream>>>(h, Wout, bout, out);
}

// Round 6
// 810.531 us; speedup vs baseline: 1.6650x; 1.2630x over previous
//
#include <hip/hip_runtime.h>
#include <cmath>

#define N_NODES   100000
#define N_EDGES   1600000
#define N_FEATS   128
#define HIDDEN    64
#define N_CLASSES 40
#define N_LAYERS  8
#define ALPHA     0.1f
#define LAMDA     0.5f

#define SCAN_ITEMS 8
#define SCAN_BLK   256
#define SCAN_TILE  (SCAN_ITEMS * SCAN_BLK)                  // 2048
#define SCAN_NBLK  ((N_NODES + SCAN_TILE - 1) / SCAN_TILE)  // 49

typedef unsigned short ushortT;
typedef unsigned int   uintT;

__device__ __forceinline__ float bf2f(ushortT u) {
    return __uint_as_float(((uintT)u) << 16);
}
__device__ __forceinline__ ushortT f2bf(float f) {
    uintT x = __float_as_uint(f);
    return (ushortT)((x + 0x7FFFu + ((x >> 16) & 1u)) >> 16);   // RNE
}

// ---------------- CSR build ----------------

__global__ __launch_bounds__(256) void k_zero_deg(int* __restrict__ deg) {
    int i = blockIdx.x * 256 + threadIdx.x;
    if (i < N_NODES) deg[i] = 0;
}

// 4 independent atomic chains per thread (latency-bound, not BW-bound)
__global__ __launch_bounds__(256) void k_count_deg(const int* __restrict__ col,
                                                   int* __restrict__ deg) {
    const int G = gridDim.x * 256;
    int e0 = blockIdx.x * 256 + threadIdx.x;
    int e1 = e0 + G, e2 = e1 + G, e3 = e2 + G;
    int c0 = (e0 < N_EDGES) ? col[e0] : -1;
    int c1 = (e1 < N_EDGES) ? col[e1] : -1;
    int c2 = (e2 < N_EDGES) ? col[e2] : -1;
    int c3 = (e3 < N_EDGES) ? col[e3] : -1;
    if (c0 >= 0) atomicAdd(&deg[c0], 1);
    if (c1 >= 0) atomicAdd(&deg[c1], 1);
    if (c2 >= 0) atomicAdd(&deg[c2], 1);
    if (c3 >= 0) atomicAdd(&deg[c3], 1);
}

// block-level exclusive scan of deg -> rowptr (partial), block totals -> bsum
__global__ __launch_bounds__(SCAN_BLK) void k_scan1(const int* __restrict__ deg,
                                                    int* __restrict__ rowptr,
                                                    int* __restrict__ bsum) {
    __shared__ int sc[SCAN_BLK];
    const int t = threadIdx.x;
    const int base = blockIdx.x * SCAN_TILE + t * SCAN_ITEMS;
    int v[SCAN_ITEMS];
    int tsum = 0;
#pragma unroll
    for (int j = 0; j < SCAN_ITEMS; ++j) {
        v[j] = (base + j < N_NODES) ? deg[base + j] : 0;
        tsum += v[j];
    }
    sc[t] = tsum;
    __syncthreads();
    for (int off = 1; off < SCAN_BLK; off <<= 1) {
        int x = (t >= off) ? sc[t - off] : 0;
        __syncthreads();
        sc[t] += x;
        __syncthreads();
    }
    int run = sc[t] - tsum;
#pragma unroll
    for (int j = 0; j < SCAN_ITEMS; ++j) {
        if (base + j < N_NODES) rowptr[base + j] = run;
        run += v[j];
    }
    if (t == SCAN_BLK - 1) bsum[blockIdx.x] = sc[SCAN_BLK - 1];
}

__global__ __launch_bounds__(SCAN_BLK) void k_scan2(int* __restrict__ bsum) {
    __shared__ int sc[SCAN_BLK];
    const int t = threadIdx.x;
    int v = (t < SCAN_NBLK) ? bsum[t] : 0;
    sc[t] = v;
    __syncthreads();
    for (int off = 1; off < SCAN_BLK; off <<= 1) {
        int x = (t >= off) ? sc[t - off] : 0;
        __syncthreads();
        sc[t] += x;
        __syncthreads();
    }
    if (t < SCAN_NBLK) bsum[t] = sc[t] - v;
}

__global__ __launch_bounds__(256) void k_scan3(int* __restrict__ rowptr,
                                               const int* __restrict__ bsum,
                                               int* __restrict__ cursor) {
    int i = blockIdx.x * 256 + threadIdx.x;
    if (i < N_NODES) {
        int r = rowptr[i] + bsum[i / SCAN_TILE];
        rowptr[i] = r;
        cursor[i] = r;
    }
    if (i == 0) rowptr[N_NODES] = N_EDGES;
}

__global__ __launch_bounds__(256) void k_dinv(const int* __restrict__ deg,
                                              float* __restrict__ dinv) {
    int i = blockIdx.x * 256 + threadIdx.x;
    if (i < N_NODES) dinv[i] = rsqrtf(1.0f + (float)deg[i]);   // +1 self-loop
}

// fill: interleaved (src, weight) int2 -> one 8B store per edge
__global__ __launch_bounds__(256) void k_fill(const int* __restrict__ row,
                                              const int* __restrict__ col,
                                              const float* __restrict__ dinv,
                                              int* __restrict__ cursor,
                                              int2* __restrict__ csr) {
    const int G = gridDim.x * 256;
    int e0 = blockIdx.x * 256 + threadIdx.x;
    int e1 = e0 + G, e2 = e1 + G, e3 = e2 + G;

    int r0 = 0, r1 = 0, r2 = 0, r3 = 0, c0 = -1, c1 = -1, c2 = -1, c3 = -1;
    if (e0 < N_EDGES) { r0 = row[e0]; c0 = col[e0]; }
    if (e1 < N_EDGES) { r1 = row[e1]; c1 = col[e1]; }
    if (e2 < N_EDGES) { r2 = row[e2]; c2 = col[e2]; }
    if (e3 < N_EDGES) { r3 = row[e3]; c3 = col[e3]; }

    int p0 = 0, p1 = 0, p2 = 0, p3 = 0;
    if (c0 >= 0) p0 = atomicAdd(&cursor[c0], 1);
    if (c1 >= 0) p1 = atomicAdd(&cursor[c1], 1);
    if (c2 >= 0) p2 = atomicAdd(&cursor[c2], 1);
    if (c3 >= 0) p3 = atomicAdd(&cursor[c3], 1);

    if (c0 >= 0) csr[p0] = make_int2(r0, __float_as_int((1.0f - ALPHA) * dinv[r0] * dinv[c0]));
    if (c1 >= 0) csr[p1] = make_int2(r1, __float_as_int((1.0f - ALPHA) * dinv[r1] * dinv[c1]));
    if (c2 >= 0) csr[p2] = make_int2(r2, __float_as_int((1.0f - ALPHA) * dinv[r2] * dinv[c2]));
    if (c3 >= 0) csr[p3] = make_int2(r3, __float_as_int((1.0f - ALPHA) * dinv[r3] * dinv[c3]));
}

// ---------------- input GEMM: h_bf = bf16(relu(x@W0+b0)), h0 = f32 same ----------------

__global__ __launch_bounds__(256) void k_gemm_in(const float* __restrict__ x,
                                                 const float* __restrict__ W0,
                                                 const float* __restrict__ b0,
                                                 ushortT* __restrict__ h_bf,
                                                 float* __restrict__ h0) {
    __shared__ float sW[N_FEATS * HIDDEN];   // 32 KB
    __shared__ float sX[64 * N_FEATS];       // 32 KB
    const int v0 = blockIdx.x * 64;
    const bool full = (v0 + 64 <= N_NODES);

    const float4* W4 = (const float4*)W0;
    for (int idx = threadIdx.x; idx < (N_FEATS * HIDDEN) / 4; idx += 256)
        ((float4*)sW)[idx] = W4[idx];
    if (full) {
        const float4* X4 = (const float4*)(x + (size_t)v0 * N_FEATS);
        for (int idx = threadIdx.x; idx < (64 * N_FEATS) / 4; idx += 256)
            ((float4*)sX)[idx] = X4[idx];
    } else {
        for (int idx = threadIdx.x; idx < 64 * N_FEATS; idx += 256) {
            int r = idx >> 7, k = idx & 127;
            int v = v0 + r;
            sX[idx] = (v < N_NODES) ? x[(size_t)v * N_FEATS + k] : 0.0f;
        }
    }
    __syncthreads();

    const int c  = threadIdx.x & 63;
    const int r0 = threadIdx.x >> 6;   // 0..3
    float acc[16];
#pragma unroll
    for (int j = 0; j < 16; ++j) acc[j] = 0.0f;

    for (int k = 0; k < N_FEATS; ++k) {
        float w = sW[k * HIDDEN + c];
#pragma unroll
        for (int j = 0; j < 16; ++j)
            acc[j] += sX[(r0 + 4 * j) * N_FEATS + k] * w;
    }

    const float bias = b0[c];
#pragma unroll
    for (int j = 0; j < 16; ++j) {
        int v = v0 + r0 + 4 * j;
        if (v < N_NODES) {
            float val = fmaxf(acc[j] + bias, 0.0f);
            h_bf[(size_t)v * HIDDEN + c] = f2bf(val);
            h0[(size_t)v * HIDDEN + c]   = val;
        }
    }
}

// ---------------- fused SpMM: buf = (1-a)*A_hat*h + a*h0 (h in bf16) ----------------
// one wave per node; lanes 0-31 even edges, 32-63 odd edges; lane holds 2 features.
// gather = 4B ushort2 per lane -> 128B per edge-row (2 cache lines).

__global__ __launch_bounds__(256) void k_spmm(const int* __restrict__ rowptr,
                                              const int2* __restrict__ csr,
                                              const float* __restrict__ dinv,
                                              const ushortT* __restrict__ h_bf,
                                              const float* __restrict__ h0,
                                              float* __restrict__ buf) {
    const int lane = threadIdx.x & 63;
    const int l32  = lane & 31;
    const int half = lane >> 5;
    const int node = (blockIdx.x * 256 + threadIdx.x) >> 6;
    if (node >= N_NODES) return;

    const int e0 = rowptr[node];
    const int e1 = rowptr[node + 1];
    const float d = dinv[node];

    float ax, ay;
    if (half == 0) {
        const ushort2 hv = *(const ushort2*)(h_bf + (size_t)node * HIDDEN + 2 * l32);
        const float2 h0v = *(const float2*)(h0 + (size_t)node * HIDDEN + 2 * l32);
        const float cs = (1.0f - ALPHA) * d * d;
        ax = cs * bf2f(hv.x) + ALPHA * h0v.x;
        ay = cs * bf2f(hv.y) + ALPHA * h0v.y;
    } else {
        ax = 0.0f; ay = 0.0f;
    }

    for (int eb = e0; eb < e1; eb += 64) {
        int n = e1 - eb;
        if (n > 64) n = 64;
        int   idx = 0;
        float w   = 0.0f;
        if (lane < n) {
            int2 e = csr[eb + lane];
            idx = e.x;
            w   = __int_as_float(e.y);
        }
        // lanes beyond n hold (0, 0.0f): shfl from them contributes 0 safely.
        for (int j = 0; j < n; j += 16) {
            int    s[8];
            float  ww[8];
            ushort2 xv[8];
#pragma unroll
            for (int u = 0; u < 8; ++u) {
                int src = j + 2 * u + half;     // < 64 always
                s[u]  = __shfl(idx, src);
                ww[u] = __shfl(w, src);
            }
#pragma unroll
            for (int u = 0; u < 8; ++u)
                xv[u] = *(const ushort2*)(h_bf + (size_t)s[u] * HIDDEN + 2 * l32);
#pragma unroll
            for (int u = 0; u < 8; ++u) {
                ax += ww[u] * bf2f(xv[u].x);
                ay += ww[u] * bf2f(xv[u].y);
            }
        }
    }

    // combine even/odd-edge halves
    ax += __shfl_xor(ax, 32);
    ay += __shfl_xor(ay, 32);
    if (half == 0) {
        float2 o; o.x = ax; o.y = ay;
        *(float2*)(buf + (size_t)node * HIDDEN + 2 * l32) = o;
    }
}

// ---------------- layer GEMM: h_bf = bf16(relu(beta*(S@W) + (1-beta)*S)) ----------------

__global__ __launch_bounds__(256) void k_gemm_layer(const float* __restrict__ S,
                                                    const float* __restrict__ W,
                                                    float beta,
                                                    ushortT* __restrict__ hout_bf) {
    __shared__ float sW[HIDDEN * HIDDEN];   // 16 KB
    __shared__ float sS[64 * HIDDEN];       // 16 KB
    const int v0 = blockIdx.x * 64;
    const bool full = (v0 + 64 <= N_NODES);

    const float4* W4 = (const float4*)W;
    for (int idx = threadIdx.x; idx < (HIDDEN * HIDDEN) / 4; idx += 256)
        ((float4*)sW)[idx] = W4[idx];
    if (full) {
        const float4* S4 = (const float4*)(S + (size_t)v0 * HIDDEN);
        for (int idx = threadIdx.x; idx < (64 * HIDDEN) / 4; idx += 256)
            ((float4*)sS)[idx] = S4[idx];
    } else {
        for (int idx = threadIdx.x; idx < 64 * HIDDEN; idx += 256) {
            int r = idx >> 6, k = idx & 63;
            int v = v0 + r;
            sS[idx] = (v < N_NODES) ? S[(size_t)v * HIDDEN + k] : 0.0f;
        }
    }
    __syncthreads();

    const int c  = threadIdx.x & 63;
    const int r0 = threadIdx.x >> 6;
    float acc[16];
#pragma unroll
    for (int j = 0; j < 16; ++j) acc[j] = 0.0f;

    for (int k = 0; k < HIDDEN; ++k) {
        float w = sW[k * HIDDEN + c];
#pragma unroll
        for (int j = 0; j < 16; ++j)
            acc[j] += sS[(r0 + 4 * j) * HIDDEN + k] * w;
    }

#pragma unroll
    for (int j = 0; j < 16; ++j) {
        int r = r0 + 4 * j;
        int v = v0 + r;
        if (v < N_NODES) {
            float s   = sS[r * HIDDEN + c];
            float val = fmaxf(beta * acc[j] + (1.0f - beta) * s, 0.0f);
            hout_bf[(size_t)v * HIDDEN + c] = f2bf(val);
        }
    }
}

// ---------------- output GEMM: out = h @ W_out + b_out (h in bf16) ----------------

__global__ __launch_bounds__(256) void k_gemm_out(const ushortT* __restrict__ h_bf,
                                                  const float* __restrict__ Wout,
                                                  const float* __restrict__ bout,
                                                  float* __restrict__ out) {
    __shared__ float sW[HIDDEN * N_CLASSES];  // 10 KB
    __shared__ float sH[64 * HIDDEN];         // 16 KB
    const int v0 = blockIdx.x * 64;
    const bool full = (v0 + 64 <= N_NODES);

    for (int idx = threadIdx.x; idx < HIDDEN * N_CLASSES; idx += 256)
        sW[idx] = Wout[idx];
    if (full) {
        const ushort4* H4 = (const ushort4*)(h_bf + (size_t)v0 * HIDDEN);
        for (int idx = threadIdx.x; idx < (64 * HIDDEN) / 4; idx += 256) {
            ushort4 u = H4[idx];
            sH[idx * 4 + 0] = bf2f(u.x);
            sH[idx * 4 + 1] = bf2f(u.y);
            sH[idx * 4 + 2] = bf2f(u.z);
            sH[idx * 4 + 3] = bf2f(u.w);
        }
    } else {
        for (int idx = threadIdx.x; idx < 64 * HIDDEN; idx += 256) {
            int r = idx >> 6, k = idx & 63;
            int v = v0 + r;
            sH[idx] = (v < N_NODES) ? bf2f(h_bf[(size_t)v * HIDDEN + k]) : 0.0f;
        }
    }
    __syncthreads();

    for (int idx = threadIdx.x; idx < 64 * N_CLASSES; idx += 256) {
        int r = idx / N_CLASSES, c = idx % N_CLASSES;
        int v = v0 + r;
        if (v < N_NODES) {
            float acc = bout[c];
#pragma unroll 8
            for (int k = 0; k < HIDDEN; ++k)
                acc += sH[r * HIDDEN + k] * sW[k * N_CLASSES + c];
            out[(size_t)v * N_CLASSES + c] = acc;
        }
    }
}

// ---------------- launch ----------------

extern "C" void kernel_launch(void* const* d_in, const int* in_sizes, int n_in,
                              void* d_out, int out_size, void* d_ws, size_t ws_size,
                              hipStream_t stream) {
    const float* x    = (const float*)d_in[0];
    const int*   ei   = (const int*)d_in[1];
    const float* W0   = (const float*)d_in[2];
    const float* b0   = (const float*)d_in[3];
    const float* Wl   = (const float*)d_in[4];
    const float* Wout = (const float*)d_in[5];
    const float* bout = (const float*)d_in[6];
    float* out = (float*)d_out;

    const int* row = ei;             // edge_index[0] = source
    const int* col = ei + N_EDGES;   // edge_index[1] = target

    char* ws = (char*)d_ws;
    size_t off = 0;
    auto alloc = [&](size_t bytes) -> void* {
        void* p = ws + off;
        off += (bytes + 255) & ~(size_t)255;
        return p;
    };
    int*    deg    = (int*)alloc((size_t)N_NODES * 4);
    int*    rowptr = (int*)alloc((size_t)(N_NODES + 1) * 4);
    int*    cursor = (int*)alloc((size_t)N_NODES * 4);
    int*    bsum   = (int*)alloc((size_t)SCAN_NBLK * 4);
    int2*   csr    = (int2*)alloc((size_t)N_EDGES * 8);
    float*  dinv   = (float*)alloc((size_t)N_NODES * 4);
    float*  h0     = (float*)alloc((size_t)N_NODES * HIDDEN * 4);
    float*  buf    = (float*)alloc((size_t)N_NODES * HIDDEN * 4);
    ushortT* h_bf  = (ushortT*)alloc((size_t)N_NODES * HIDDEN * 2);

    const int gN   = (N_NODES + 255) / 256;
    const int gRow = (N_NODES + 63) / 64;
    const int gSpm = (N_NODES * 64 + 255) / 256;           // wave per node
    const int gE4  = (N_EDGES + 4 * 256 - 1) / (4 * 256);  // 4 edges per thread

    // CSR build (by target node)
    k_zero_deg <<<gN, 256, 0, stream>>>(deg);
    k_count_deg<<<gE4, 256, 0, stream>>>(col, deg);
    k_scan1    <<<SCAN_NBLK, SCAN_BLK, 0, stream>>>(deg, rowptr, bsum);
    k_scan2    <<<1, SCAN_BLK, 0, stream>>>(bsum);
    k_scan3    <<<gN, 256, 0, stream>>>(rowptr, bsum, cursor);
    k_dinv     <<<gN, 256, 0, stream>>>(deg, dinv);
    k_fill     <<<gE4, 256, 0, stream>>>(row, col, dinv, cursor, csr);

    // h = relu(x@W0 + b0); h0 = h (f32); h_bf = bf16(h)
    k_gemm_in<<<gRow, 256, 0, stream>>>(x, W0, b0, h_bf, h0);

    for (int i = 0; i < N_LAYERS; ++i) {
        float beta = logf(LAMDA / (float)(i + 1) + 1.0f);
        // buf = (1-a)*A_hat*h + a*h0   (gathers bf16 h, accumulates f32)
        k_spmm<<<gSpm, 256, 0, stream>>>(rowptr, csr, dinv, h_bf, h0, buf);
        // h_bf = bf16(relu(beta*(buf@Wl[i]) + (1-beta)*buf))
        k_gemm_layer<<<gRow, 256, 0, stream>>>(buf, Wl + (size_t)i * HIDDEN * HIDDEN,
                                               beta, h_bf);
    }

    // out = h @ W_out + b_out
    k_gemm_out<<<gRow, 256, 0, stream>>>(h_bf, Wout, bout, out);
}

// Round 7
// 798.048 us; speedup vs baseline: 1.6910x; 1.0156x over previous
//
#include <hip/hip_runtime.h>
#include <cmath>

#define N_NODES   100000
#define N_EDGES   1600000
#define N_FEATS   128
#define HIDDEN    64
#define N_CLASSES 40
#define N_LAYERS  8
#define ALPHA     0.1f
#define LAMDA     0.5f

#define SCAN_ITEMS 8
#define SCAN_BLK   256
#define SCAN_TILE  (SCAN_ITEMS * SCAN_BLK)                  // 2048
#define SCAN_NBLK  ((N_NODES + SCAN_TILE - 1) / SCAN_TILE)  // 49

#define FILL_RANGES 8
#define RANGE_SIZE  ((N_NODES + FILL_RANGES - 1) / FILL_RANGES)  // 12500
#define FILL_BLOCKS 1024   // multiple of 8; blockIdx%8 = range (XCD round-robin heuristic)

typedef unsigned short ushortT;
typedef unsigned int   uintT;

__device__ __forceinline__ float bf2f(ushortT u) {
    return __uint_as_float(((uintT)u) << 16);
}
__device__ __forceinline__ ushortT f2bf(float f) {
    uintT x = __float_as_uint(f);
    return (ushortT)((x + 0x7FFFu + ((x >> 16) & 1u)) >> 16);   // RNE
}

// ---------------- CSR build ----------------

__global__ __launch_bounds__(256) void k_zero_deg(int* __restrict__ deg) {
    int i = blockIdx.x * 256 + threadIdx.x;
    if (i < N_NODES) deg[i] = 0;
}

// 4 independent atomic chains per thread (latency-bound, not BW-bound)
__global__ __launch_bounds__(256) void k_count_deg(const int* __restrict__ col,
                                                   int* __restrict__ deg) {
    const int G = gridDim.x * 256;
    int e0 = blockIdx.x * 256 + threadIdx.x;
    int e1 = e0 + G, e2 = e1 + G, e3 = e2 + G;
    int c0 = (e0 < N_EDGES) ? col[e0] : -1;
    int c1 = (e1 < N_EDGES) ? col[e1] : -1;
    int c2 = (e2 < N_EDGES) ? col[e2] : -1;
    int c3 = (e3 < N_EDGES) ? col[e3] : -1;
    if (c0 >= 0) atomicAdd(&deg[c0], 1);
    if (c1 >= 0) atomicAdd(&deg[c1], 1);
    if (c2 >= 0) atomicAdd(&deg[c2], 1);
    if (c3 >= 0) atomicAdd(&deg[c3], 1);
}

// block-level exclusive scan of deg -> rowptr (partial), block totals -> bsum
__global__ __launch_bounds__(SCAN_BLK) void k_scan1(const int* __restrict__ deg,
                                                    int* __restrict__ rowptr,
                                                    int* __restrict__ bsum) {
    __shared__ int sc[SCAN_BLK];
    const int t = threadIdx.x;
    const int base = blockIdx.x * SCAN_TILE + t * SCAN_ITEMS;
    int v[SCAN_ITEMS];
    int tsum = 0;
#pragma unroll
    for (int j = 0; j < SCAN_ITEMS; ++j) {
        v[j] = (base + j < N_NODES) ? deg[base + j] : 0;
        tsum += v[j];
    }
    sc[t] = tsum;
    __syncthreads();
    for (int off = 1; off < SCAN_BLK; off <<= 1) {
        int x = (t >= off) ? sc[t - off] : 0;
        __syncthreads();
        sc[t] += x;
        __syncthreads();
    }
    int run = sc[t] - tsum;
#pragma unroll
    for (int j = 0; j < SCAN_ITEMS; ++j) {
        if (base + j < N_NODES) rowptr[base + j] = run;
        run += v[j];
    }
    if (t == SCAN_BLK - 1) bsum[blockIdx.x] = sc[SCAN_BLK - 1];
}

__global__ __launch_bounds__(SCAN_BLK) void k_scan2(int* __restrict__ bsum) {
    __shared__ int sc[SCAN_BLK];
    const int t = threadIdx.x;
    int v = (t < SCAN_NBLK) ? bsum[t] : 0;
    sc[t] = v;
    __syncthreads();
    for (int off = 1; off < SCAN_BLK; off <<= 1) {
        int x = (t >= off) ? sc[t - off] : 0;
        __syncthreads();
        sc[t] += x;
        __syncthreads();
    }
    if (t < SCAN_NBLK) bsum[t] = sc[t] - v;
}

__global__ __launch_bounds__(256) void k_scan3(int* __restrict__ rowptr,
                                               const int* __restrict__ bsum,
                                               int* __restrict__ cursor) {
    int i = blockIdx.x * 256 + threadIdx.x;
    if (i < N_NODES) {
        int r = rowptr[i] + bsum[i / SCAN_TILE];
        rowptr[i] = r;
        cursor[i] = r;
    }
    if (i == 0) rowptr[N_NODES] = N_EDGES;
}

__global__ __launch_bounds__(256) void k_dinv(const int* __restrict__ deg,
                                              float* __restrict__ dinv) {
    int i = blockIdx.x * 256 + threadIdx.x;
    if (i < N_NODES) dinv[i] = rsqrtf(1.0f + (float)deg[i]);   // +1 self-loop
}

// fill, XCD-range-partitioned: blockIdx%8 = node range; with round-robin
// block->XCD dispatch each 1.6MB csr window is written by one XCD's L2,
// so the 8 edges per 64B line merge before writeback.
__global__ __launch_bounds__(256) void k_fill(const int* __restrict__ row,
                                              const int* __restrict__ col,
                                              const float* __restrict__ dinv,
                                              int* __restrict__ cursor,
                                              int2* __restrict__ csr) {
    const int range = blockIdx.x & (FILL_RANGES - 1);
    const int lo = range * RANGE_SIZE;
    const int hi = lo + RANGE_SIZE;
    const int stride = (gridDim.x >> 3) * 256;
    for (int e = (blockIdx.x >> 3) * 256 + threadIdx.x; e < N_EDGES; e += stride) {
        int c = col[e];
        if (c >= lo && c < hi) {
            int r = row[e];
            int pos = atomicAdd(&cursor[c], 1);
            csr[pos] = make_int2(r, __float_as_int((1.0f - ALPHA) * dinv[r] * dinv[c]));
        }
    }
}

// ---------------- input GEMM: h_bf = h0_bf = bf16(relu(x@W0+b0)) ----------------

__global__ __launch_bounds__(256) void k_gemm_in(const float* __restrict__ x,
                                                 const float* __restrict__ W0,
                                                 const float* __restrict__ b0,
                                                 ushortT* __restrict__ h_bf,
                                                 ushortT* __restrict__ h0_bf) {
    __shared__ float sW[N_FEATS * HIDDEN];   // 32 KB
    __shared__ float sX[64 * N_FEATS];       // 32 KB
    const int v0 = blockIdx.x * 64;
    const bool full = (v0 + 64 <= N_NODES);

    const float4* W4 = (const float4*)W0;
    for (int idx = threadIdx.x; idx < (N_FEATS * HIDDEN) / 4; idx += 256)
        ((float4*)sW)[idx] = W4[idx];
    if (full) {
        const float4* X4 = (const float4*)(x + (size_t)v0 * N_FEATS);
        for (int idx = threadIdx.x; idx < (64 * N_FEATS) / 4; idx += 256)
            ((float4*)sX)[idx] = X4[idx];
    } else {
        for (int idx = threadIdx.x; idx < 64 * N_FEATS; idx += 256) {
            int r = idx >> 7, k = idx & 127;
            int v = v0 + r;
            sX[idx] = (v < N_NODES) ? x[(size_t)v * N_FEATS + k] : 0.0f;
        }
    }
    __syncthreads();

    const int c  = threadIdx.x & 63;
    const int r0 = threadIdx.x >> 6;   // 0..3
    float acc[16];
#pragma unroll
    for (int j = 0; j < 16; ++j) acc[j] = 0.0f;

    for (int k = 0; k < N_FEATS; ++k) {
        float w = sW[k * HIDDEN + c];
#pragma unroll
        for (int j = 0; j < 16; ++j)
            acc[j] += sX[(r0 + 4 * j) * N_FEATS + k] * w;
    }

    const float bias = b0[c];
#pragma unroll
    for (int j = 0; j < 16; ++j) {
        int v = v0 + r0 + 4 * j;
        if (v < N_NODES) {
            ushortT val = f2bf(fmaxf(acc[j] + bias, 0.0f));
            h_bf [(size_t)v * HIDDEN + c] = val;
            h0_bf[(size_t)v * HIDDEN + c] = val;
        }
    }
}

// ---------------- fused SpMM: buf_bf = bf16((1-a)*A_hat*h + a*h0) ----------------
// one wave per node; lanes 0-31 even edges, 32-63 odd edges; lane holds 2 features.

__global__ __launch_bounds__(256) void k_spmm(const int* __restrict__ rowptr,
                                              const int2* __restrict__ csr,
                                              const float* __restrict__ dinv,
                                              const ushortT* __restrict__ h_bf,
                                              const ushortT* __restrict__ h0_bf,
                                              ushortT* __restrict__ buf_bf) {
    const int lane = threadIdx.x & 63;
    const int l32  = lane & 31;
    const int half = lane >> 5;
    const int node = (blockIdx.x * 256 + threadIdx.x) >> 6;
    if (node >= N_NODES) return;

    const int e0 = rowptr[node];
    const int e1 = rowptr[node + 1];
    const float d = dinv[node];

    float ax, ay;
    if (half == 0) {
        const ushort2 hv  = *(const ushort2*)(h_bf  + (size_t)node * HIDDEN + 2 * l32);
        const ushort2 h0v = *(const ushort2*)(h0_bf + (size_t)node * HIDDEN + 2 * l32);
        const float cs = (1.0f - ALPHA) * d * d;
        ax = cs * bf2f(hv.x) + ALPHA * bf2f(h0v.x);
        ay = cs * bf2f(hv.y) + ALPHA * bf2f(h0v.y);
    } else {
        ax = 0.0f; ay = 0.0f;
    }

    for (int eb = e0; eb < e1; eb += 64) {
        int n = e1 - eb;
        if (n > 64) n = 64;
        int   idx = 0;
        float w   = 0.0f;
        if (lane < n) {
            int2 e = csr[eb + lane];
            idx = e.x;
            w   = __int_as_float(e.y);
        }
        // lanes beyond n hold (0, 0.0f): shfl from them contributes 0 safely.
        for (int j = 0; j < n; j += 16) {
            int    s[8];
            float  ww[8];
            ushort2 xv[8];
#pragma unroll
            for (int u = 0; u < 8; ++u) {
                int src = j + 2 * u + half;     // < 64 always
                s[u]  = __shfl(idx, src);
                ww[u] = __shfl(w, src);
            }
#pragma unroll
            for (int u = 0; u < 8; ++u)
                xv[u] = *(const ushort2*)(h_bf + (size_t)s[u] * HIDDEN + 2 * l32);
#pragma unroll
            for (int u = 0; u < 8; ++u) {
                ax += ww[u] * bf2f(xv[u].x);
                ay += ww[u] * bf2f(xv[u].y);
            }
        }
    }

    // combine even/odd-edge halves
    ax += __shfl_xor(ax, 32);
    ay += __shfl_xor(ay, 32);
    if (half == 0) {
        ushort2 o; o.x = f2bf(ax); o.y = f2bf(ay);
        *(ushort2*)(buf_bf + (size_t)node * HIDDEN + 2 * l32) = o;
    }
}

// ---------------- layer GEMM: h_bf = bf16(relu(beta*(S@W) + (1-beta)*S)) ----------------

__global__ __launch_bounds__(256) void k_gemm_layer(const ushortT* __restrict__ S_bf,
                                                    const float* __restrict__ W,
                                                    float beta,
                                                    ushortT* __restrict__ hout_bf) {
    __shared__ float sW[HIDDEN * HIDDEN];   // 16 KB
    __shared__ float sS[64 * HIDDEN];       // 16 KB
    const int v0 = blockIdx.x * 64;
    const bool full = (v0 + 64 <= N_NODES);

    const float4* W4 = (const float4*)W;
    for (int idx = threadIdx.x; idx < (HIDDEN * HIDDEN) / 4; idx += 256)
        ((float4*)sW)[idx] = W4[idx];
    if (full) {
        const ushort4* S4 = (const ushort4*)(S_bf + (size_t)v0 * HIDDEN);
        for (int idx = threadIdx.x; idx < (64 * HIDDEN) / 4; idx += 256) {
            ushort4 u = S4[idx];
            sS[idx * 4 + 0] = bf2f(u.x);
            sS[idx * 4 + 1] = bf2f(u.y);
            sS[idx * 4 + 2] = bf2f(u.z);
            sS[idx * 4 + 3] = bf2f(u.w);
        }
    } else {
        for (int idx = threadIdx.x; idx < 64 * HIDDEN; idx += 256) {
            int r = idx >> 6, k = idx & 63;
            int v = v0 + r;
            sS[idx] = (v < N_NODES) ? bf2f(S_bf[(size_t)v * HIDDEN + k]) : 0.0f;
        }
    }
    __syncthreads();

    const int c  = threadIdx.x & 63;
    const int r0 = threadIdx.x >> 6;
    float acc[16];
#pragma unroll
    for (int j = 0; j < 16; ++j) acc[j] = 0.0f;

    for (int k = 0; k < HIDDEN; ++k) {
        float w = sW[k * HIDDEN + c];
#pragma unroll
        for (int j = 0; j < 16; ++j)
            acc[j] += sS[(r0 + 4 * j) * HIDDEN + k] * w;
    }

#pragma unroll
    for (int j = 0; j < 16; ++j) {
        int r = r0 + 4 * j;
        int v = v0 + r;
        if (v < N_NODES) {
            float s   = sS[r * HIDDEN + c];
            float val = fmaxf(beta * acc[j] + (1.0f - beta) * s, 0.0f);
            hout_bf[(size_t)v * HIDDEN + c] = f2bf(val);
        }
    }
}

// ---------------- output GEMM: out = h @ W_out + b_out (h in bf16) ----------------

__global__ __launch_bounds__(256) void k_gemm_out(const ushortT* __restrict__ h_bf,
                                                  const float* __restrict__ Wout,
                                                  const float* __restrict__ bout,
                                                  float* __restrict__ out) {
    __shared__ float sW[HIDDEN * N_CLASSES];  // 10 KB
    __shared__ float sH[64 * HIDDEN];         // 16 KB
    const int v0 = blockIdx.x * 64;
    const bool full = (v0 + 64 <= N_NODES);

    for (int idx = threadIdx.x; idx < HIDDEN * N_CLASSES; idx += 256)
        sW[idx] = Wout[idx];
    if (full) {
        const ushort4* H4 = (const ushort4*)(h_bf + (size_t)v0 * HIDDEN);
        for (int idx = threadIdx.x; idx < (64 * HIDDEN) / 4; idx += 256) {
            ushort4 u = H4[idx];
            sH[idx * 4 + 0] = bf2f(u.x);
            sH[idx * 4 + 1] = bf2f(u.y);
            sH[idx * 4 + 2] = bf2f(u.z);
            sH[idx * 4 + 3] = bf2f(u.w);
        }
    } else {
        for (int idx = threadIdx.x; idx < 64 * HIDDEN; idx += 256) {
            int r = idx >> 6, k = idx & 63;
            int v = v0 + r;
            sH[idx] = (v < N_NODES) ? bf2f(h_bf[(size_t)v * HIDDEN + k]) : 0.0f;
        }
    }
    __syncthreads();

    for (int idx = threadIdx.x; idx < 64 * N_CLASSES; idx += 256) {
        int r = idx / N_CLASSES, c = idx % N_CLASSES;
        int v = v0 + r;
        if (v < N_NODES) {
            float acc = bout[c];
#pragma unroll 8
            for (int k = 0; k < HIDDEN; ++k)
                acc += sH[r * HIDDEN + k] * sW[k * N_CLASSES + c];
            out[(size_t)v * N_CLASSES + c] = acc;
        }
    }
}

// ---------------- launch ----------------

extern "C" void kernel_launch(void* const* d_in, const int* in_sizes, int n_in,
                              void* d_out, int out_size, void* d_ws, size_t ws_size,
                              hipStream_t stream) {
    const float* x    = (const float*)d_in[0];
    const int*   ei   = (const int*)d_in[1];
    const float* W0   = (const float*)d_in[2];
    const float* b0   = (const float*)d_in[3];
    const float* Wl   = (const float*)d_in[4];
    const float* Wout = (const float*)d_in[5];
    const float* bout = (const float*)d_in[6];
    float* out = (float*)d_out;

    const int* row = ei;             // edge_index[0] = source
    const int* col = ei + N_EDGES;   // edge_index[1] = target

    char* ws = (char*)d_ws;
    size_t off = 0;
    auto alloc = [&](size_t bytes) -> void* {
        void* p = ws + off;
        off += (bytes + 255) & ~(size_t)255;
        return p;
    };
    int*     deg    = (int*)alloc((size_t)N_NODES * 4);
    int*     rowptr = (int*)alloc((size_t)(N_NODES + 1) * 4);
    int*     cursor = (int*)alloc((size_t)N_NODES * 4);
    int*     bsum   = (int*)alloc((size_t)SCAN_NBLK * 4);
    int2*    csr    = (int2*)alloc((size_t)N_EDGES * 8);
    float*   dinv   = (float*)alloc((size_t)N_NODES * 4);
    ushortT* h0_bf  = (ushortT*)alloc((size_t)N_NODES * HIDDEN * 2);
    ushortT* buf_bf = (ushortT*)alloc((size_t)N_NODES * HIDDEN * 2);
    ushortT* h_bf   = (ushortT*)alloc((size_t)N_NODES * HIDDEN * 2);

    const int gN   = (N_NODES + 255) / 256;
    const int gRow = (N_NODES + 63) / 64;
    const int gSpm = (N_NODES * 64 + 255) / 256;           // wave per node
    const int gE4  = (N_EDGES + 4 * 256 - 1) / (4 * 256);  // 4 edges per thread

    // CSR build (by target node)
    k_zero_deg <<<gN, 256, 0, stream>>>(deg);
    k_count_deg<<<gE4, 256, 0, stream>>>(col, deg);
    k_scan1    <<<SCAN_NBLK, SCAN_BLK, 0, stream>>>(deg, rowptr, bsum);
    k_scan2    <<<1, SCAN_BLK, 0, stream>>>(bsum);
    k_scan3    <<<gN, 256, 0, stream>>>(rowptr, bsum, cursor);
    k_dinv     <<<gN, 256, 0, stream>>>(deg, dinv);
    k_fill     <<<FILL_BLOCKS, 256, 0, stream>>>(row, col, dinv, cursor, csr);

    // h = relu(x@W0 + b0) -> h_bf, h0_bf
    k_gemm_in<<<gRow, 256, 0, stream>>>(x, W0, b0, h_bf, h0_bf);

    for (int i = 0; i < N_LAYERS; ++i) {
        float beta = logf(LAMDA / (float)(i + 1) + 1.0f);
        // buf = (1-a)*A_hat*h + a*h0   (bf16 gather, f32 accumulate, bf16 out)
        k_spmm<<<gSpm, 256, 0, stream>>>(rowptr, csr, dinv, h_bf, h0_bf, buf_bf);
        // h_bf = bf16(relu(beta*(buf@Wl[i]) + (1-beta)*buf))
        k_gemm_layer<<<gRow, 256, 0, stream>>>(buf_bf, Wl + (size_t)i * HIDDEN * HIDDEN,
                                               beta, h_bf);
    }

    // out = h @ W_out + b_out
    k_gemm_out<<<gRow, 256, 0, stream>>>(h_bf, Wout, bout, out);
}